// Round 17
// baseline (650.485 us; speedup 1.0000x reference)
//
#include <hip/hip_runtime.h>
#include <math.h>

typedef unsigned short u16;
typedef unsigned int u32;
typedef unsigned long long u64;
typedef __attribute__((ext_vector_type(8))) short bf16x8;
typedef __attribute__((ext_vector_type(4))) float f32x4;

#define MFMA16(a,b,c) __builtin_amdgcn_mfma_f32_16x16x32_bf16(a,b,c,0,0,0)

typedef __attribute__((address_space(1))) const unsigned int as1_u32;
typedef __attribute__((address_space(3))) unsigned int as3_u32;
__device__ __forceinline__ void gld16(const u16* g, u16* l){
  __builtin_amdgcn_global_load_lds((as1_u32*)g, (as3_u32*)l, 16, 0, 0);
}

__device__ __forceinline__ u16 f2bf(float x){
  union { float f; u32 u; } v; v.f = x;
  u32 u = v.u;
  return (u16)((u + 0x7fffu + ((u>>16)&1u)) >> 16);
}

__device__ __forceinline__ void memfence(){ asm volatile("" ::: "memory"); }

union B8 { bf16x8 v; u32 u[4]; uint4 q; };

// ---------------- K0 (merged): fold BN into bf16 weights, all 4 sets ----------
__global__ void k0_prep4(
    const float* w0,const float* b0,const float* g0,const float* e0,const float* m0,const float* v0,
    const float* w1,const float* b1,const float* g1,const float* e1,const float* m1,const float* v1,
    const float* w2,const float* b2,const float* g2,const float* e2,const float* m2,const float* v2,
    const float* w3,const float* b3,const float* g3,const float* e3,const float* m3,const float* v3,
    float extraK, u16* wz, float* dz)
{
  int m = blockIdx.x;
  const float* W[4]={w0,w1,w2,w3}; const float* B[4]={b0,b1,b2,b3};
  const float* G[4]={g0,g1,g2,g3}; const float* E[4]={e0,e1,e2,e3};
  const float* M[4]={m0,m1,m2,m3}; const float* V[4]={v0,v1,v2,v3};
  const float* wm=W[m]; const float* bias=B[m]; const float* gamma=G[m];
  const float* beta=E[m]; const float* mean=M[m]; const float* var=V[m];
  float extra = (m==1) ? extraK : 1.0f;
  u16* wdst = wz + m*4096;
  float* ddst = dz + m*64;

  int t = threadIdx.x;
  if (t < 64){
    float a0 = gamma[t] * rsqrtf(var[t] + 1e-5f);
    ddst[t] = (beta[t] + (bias[t] - mean[t]) * a0) * extra;
  }
  for (int i = t; i < 4096; i += 256){
    int o = i >> 6;
    float a0 = gamma[o] * rsqrtf(var[o] + 1e-5f);
    wdst[i] = f2bf(wm[i] * a0 * extra);
  }
}

// ---------------- K1: QKV projection + BN (R16 body, frozen) ----------
__global__ __launch_bounds__(256,3)
void k1_qkv(const float* __restrict__ f, const u16* __restrict__ wz,
            const float* __restrict__ dz, u16* __restrict__ q,
            u16* __restrict__ kk_, u16* __restrict__ vt)
{
  int bid = blockIdx.x;
  int b  = bid >> 8;
  int ht = (bid >> 3) & 31;
  int wt = bid & 7;
  int tid = threadIdx.x;
  int wv = tid >> 6, lane = tid & 63;
  int l15 = lane & 15, l4 = lane >> 4;
  int h0 = ht * 16;
  int w0 = wt * 64 + wv * 16;

  bf16x8 wa[3][4][2];
  #pragma unroll
  for (int mt=0; mt<3; mt++)
    #pragma unroll
    for (int m=0;m<4;m++)
      #pragma unroll
      for (int ks=0;ks<2;ks++){
        B8 t; t.q = *(const uint4*)(wz + mt*4096 + (m*16+l15)*64 + ks*32 + l4*8);
        wa[mt][m][ks] = t.v;
      }
  f32x4 dv[3][4];
  #pragma unroll
  for (int mt=0;mt<3;mt++)
    #pragma unroll
    for (int m=0;m<4;m++)
      dv[mt][m] = *(const f32x4*)(dz + mt*64 + m*16 + l4*4);

  __shared__ u16 vstage[4][8704];
  u16* vs = vstage[wv];

  B8 bf[2];
  #pragma unroll
  for (int ks=0;ks<2;ks++)
    #pragma unroll
    for (int jj=0;jj<4;jj++){
      int c0 = ks*32 + l4*8 + jj*2;
      size_t i0 = ((size_t)(b*64 + c0)*512 + h0)*512 + w0 + l15;
      bf[ks].u[jj] = (u32)f2bf(f[i0]) | ((u32)f2bf(f[i0 + 262144]) << 16);
    }

  for (int hh=0; hh<16; hh++){
    int h = h0 + hh;
    B8 bfn[2];
    if (hh < 15){
      #pragma unroll
      for (int ks=0;ks<2;ks++)
        #pragma unroll
        for (int jj=0;jj<4;jj++){
          int c0 = ks*32 + l4*8 + jj*2;
          size_t i0 = ((size_t)(b*64 + c0)*512 + h + 1)*512 + w0 + l15;
          bfn[ks].u[jj] = (u32)f2bf(f[i0]) | ((u32)f2bf(f[i0 + 262144]) << 16);
        }
    }
    #pragma unroll
    for (int mt=0; mt<3; mt++){
      f32x4 acc[4];
      #pragma unroll
      for (int m=0;m<4;m++) acc[m] = (f32x4){0.f,0.f,0.f,0.f};
      #pragma unroll
      for (int m=0;m<4;m++)
        #pragma unroll
        for (int ks=0;ks<2;ks++)
          acc[m] = MFMA16(wa[mt][m][ks], bf[ks].v, acc[m]);
      #pragma unroll
      for (int m=0;m<4;m++)
        #pragma unroll
        for (int r=0;r<4;r++){
          float val = acc[m][r] + dv[mt][m][r];
          u16 bv = f2bf(val);
          int o = m*16 + l4*4 + r;
          if (mt==0)      q  [((size_t)(b*64+o)*512 + h)*512 + w0 + l15] = bv;
          else if (mt==1) kk_[((size_t)(b*64+o)*512 + h)*512 + w0 + l15] = bv;
          else            vs[o*136 + l15*8 + (hh&7)] = bv;
        }
    }
    bf[0] = bfn[0]; bf[1] = bfn[1];
    if ((hh&7)==7){
      __syncthreads();
      int hbg = (h - 7) >> 3;    // global 8-h block index
      #pragma unroll
      for (int rr=0; rr<16; rr++){
        int o = rr*4 + l4;
        uint4 d = *(const uint4*)(vs + o*136 + l15*8);
        *(uint4*)(vt + (size_t)(b*64+o)*262144 + (size_t)hbg*4096
                     + (size_t)(w0+l15)*8) = d;
      }
      __syncthreads();
    }
  }
}

// ---------------- K23 v12: flash attention, 64-g iterations (two 32-g halves) ----
// grid 1024, 512 thr (8 waves). QBLK=128, 8 iters of 64 g. All per-half layouts
// identical to v11 (K rows padded 520, V granule swizzle, wave-private P).
// Halved per-iteration overhead: 4 barriers + 2 counted-vmcnt per 64 g (was 6+4),
// one softmax reduction block per 64 g (was two). LDS 149KB (occupancy reg-capped
// at 1 blk/CU anyway). In-order vmcnt(8): top-of-iter guarantees K(jt) landed
// (V(jt) still flying); mid-iter guarantees V(jt) landed (K(jt+1) flying).
__global__ __launch_bounds__(512,2)
void k23_attn(const u16* __restrict__ q, const u16* __restrict__ kten,
              const u16* __restrict__ vt, u16* __restrict__ o2)
{
  int phys = blockIdx.x;
  int x = phys & 7, j = phys >> 3;
  int qt = j & 3, hh = j >> 2;
  int head = x*32 + hh;
  int q0 = qt*128;
  int b = head >> 6, c = head & 63;

  int tid = threadIdx.x;
  int wv = tid >> 6, lane = tid & 63;
  int l15 = lane & 15, l4 = lane >> 4;

  const u16* qh = q    + (size_t)head*262144;
  const u16* kh = kten + (size_t)head*262144;
  const u16* vh = vt   + (size_t)head*262144;   // [hb(64)][w(512)][8h]

  __shared__ u16 KH[2][16640];  // two 32-g halves, rows padded to 520
  __shared__ u16 VH[2][16384];  // two 32-g halves, granule-swizzled
  __shared__ u16 PH[2][5120];   // P per half, [q][40] wave-private rows

  auto stageK64 = [&](int jt){
    #pragma unroll
    for (int h=0;h<2;h++){
      const u16* src = kh + (size_t)jt*32768 + h*16384;
      #pragma unroll
      for (int i=0;i<4;i++){
        int row = i*8 + wv;                     // wave-uniform per instruction
        gld16(src + (size_t)row*512 + lane*8, &KH[h][row*520 + lane*8]);
      }
    }
  };
  auto stageV64 = [&](int jt){
    #pragma unroll
    for (int h=0;h<2;h++){
      const u16* src = vh + (size_t)jt*32768 + h*16384;  // 4 hb pages each
      #pragma unroll
      for (int i=0;i<4;i++){
        int slot = i*512 + tid;
        int w = slot >> 2, cc = slot & 3;
        int hbl = (cc - (w>>1)) & 3;            // hb page feeding this LDS slot
        gld16(src + hbl*4096 + w*8, &VH[h][slot*8]);
      }
    }
  };

  // prologue: Q->regs, K(0), V(0); full drain once
  uint4 qreg[16];
  {
    const u16* qrow = qh + (size_t)(q0 + wv*16 + l15)*512;
    #pragma unroll
    for (int ks=0;ks<16;ks++) qreg[ks] = *(const uint4*)(qrow + ks*32 + l4*8);
  }
  stageK64(0); stageV64(0);
  asm volatile("s_waitcnt vmcnt(0)" ::: "memory");
  __builtin_amdgcn_s_barrier(); memfence();

  f32x4 oacc[32];
  #pragma unroll
  for (int n=0;n<32;n++) oacc[n] = (f32x4){0.f,0.f,0.f,0.f};
  float m_run[4] = {-1e30f,-1e30f,-1e30f,-1e30f};
  float l_run[4] = {0.f,0.f,0.f,0.f};

  // per-lane LDS element bases; all loop offsets are compile-time immediates
  const int kbase = l15*520 + l4*8;                              // + n*8320 + ks*32
  const int vbase = l15*32  + (((l4 + (l15>>1)) & 3) << 3);      // + n*512
  const int pbase = (wv*16 + l15)*40;                            // + l4*8
  const int prow  = (wv*16 + l4*4)*40;                           // + r*40 (+16)

  for (int jt=0; jt<8; ++jt){
    if (jt > 0){
      // K(jt) landed (leaves V(jt)'s 8 loads in flight)
      asm volatile("s_waitcnt vmcnt(8)" ::: "memory");
      __builtin_amdgcn_s_barrier(); memfence();
    }

    // ===== S phase: 64 MFMA over 64 g (4 independent 16-deep chains) =====
    f32x4 s0={0.f,0.f,0.f,0.f}, s1={0.f,0.f,0.f,0.f};
    f32x4 s2={0.f,0.f,0.f,0.f}, s3={0.f,0.f,0.f,0.f};
    __builtin_amdgcn_s_setprio(1);
    #pragma unroll
    for (int ks=0; ks<16; ++ks){
      B8 a; a.q = qreg[ks];
      B8 b0; b0.q = *(const uint4*)(&KH[0][0] + kbase + 0*8320 + ks*32);
      B8 b1; b1.q = *(const uint4*)(&KH[0][0] + kbase + 1*8320 + ks*32);
      B8 b2; b2.q = *(const uint4*)(&KH[1][0] + kbase + 0*8320 + ks*32);
      B8 b3; b3.q = *(const uint4*)(&KH[1][0] + kbase + 1*8320 + ks*32);
      s0 = MFMA16(a.v, b0.v, s0);
      s1 = MFMA16(a.v, b1.v, s1);
      s2 = MFMA16(a.v, b2.v, s2);
      s3 = MFMA16(a.v, b3.v, s3);
    }
    __builtin_amdgcn_s_setprio(0);

    // ===== wave-private online softmax over 64 g (rows wv*16 + l4*4 + r) =====
    float pm[4], fc[4];
    bool need = false;
    #pragma unroll
    for (int r=0;r<4;r++){
      float p = fmaxf(fmaxf(s0[r], s1[r]), fmaxf(s2[r], s3[r]));
      #pragma unroll
      for (int d=1; d<16; d<<=1) p = fmaxf(p, __shfl_xor(p, d, 64));
      pm[r] = p;
      need = need || (p > m_run[r] + 4.0f);
    }
    if (__any(need ? 1 : 0)){
      #pragma unroll
      for (int r=0;r<4;r++){
        float mn = fmaxf(m_run[r], pm[r]);
        fc[r] = exp2f(m_run[r] - mn);
        m_run[r] = mn;
      }
      #pragma unroll
      for (int n=0;n<32;n++)
        #pragma unroll
        for (int r=0;r<4;r++) oacc[n][r] *= fc[r];
    } else {
      fc[0]=fc[1]=fc[2]=fc[3]=1.0f;
    }
    #pragma unroll
    for (int r=0;r<4;r++){
      float e0 = exp2f(s0[r] - m_run[r]);
      float e1 = exp2f(s1[r] - m_run[r]);
      float e2 = exp2f(s2[r] - m_run[r]);
      float e3 = exp2f(s3[r] - m_run[r]);
      float s = (e0+e1)+(e2+e3);
      #pragma unroll
      for (int d=1; d<16; d<<=1) s += __shfl_xor(s, d, 64);
      l_run[r] = l_run[r]*fc[r] + s;
      PH[0][prow + r*40 + l15]      = f2bf(e0);
      PH[0][prow + r*40 + 16 + l15] = f2bf(e1);
      PH[1][prow + r*40 + l15]      = f2bf(e2);
      PH[1][prow + r*40 + 16 + l15] = f2bf(e3);
    }

    // barrier: all waves done reading K halves -> free for K(jt+1)
    asm volatile("s_waitcnt lgkmcnt(0)" ::: "memory");
    __builtin_amdgcn_s_barrier(); memfence();

    if (jt < 7) stageK64(jt+1);
    // V(jt) landed (leaves K(jt+1)'s 8 in flight); last iter: drain
    if (jt < 7) { asm volatile("s_waitcnt vmcnt(8)" ::: "memory"); }
    else        { asm volatile("s_waitcnt vmcnt(0)" ::: "memory"); }
    __builtin_amdgcn_s_barrier(); memfence();

    // ===== PV phase: O[own 16 q][512 w] += P(16x64) * V(64x512) =====
    B8 paA; paA.q = *(const uint4*)(&PH[0][0] + pbase + l4*8);
    B8 paB; paB.q = *(const uint4*)(&PH[1][0] + pbase + l4*8);
    __builtin_amdgcn_s_setprio(1);
    #pragma unroll
    for (int n=0;n<32;n++){
      B8 b0; b0.q = *(const uint4*)(&VH[0][0] + vbase + n*512);
      B8 b1; b1.q = *(const uint4*)(&VH[1][0] + vbase + n*512);
      oacc[n] = MFMA16(paA.v, b0.v, oacc[n]);
      oacc[n] = MFMA16(paB.v, b1.v, oacc[n]);
    }
    __builtin_amdgcn_s_setprio(0);

    if (jt < 7){
      // all waves done reading V halves + P -> refill V(jt+1)
      asm volatile("s_waitcnt lgkmcnt(0)" ::: "memory");
      __builtin_amdgcn_s_barrier(); memfence();
      stageV64(jt+1);
      // no wait: next iter's top vmcnt(8) / mid vmcnt(8) cover K/V ordering
    }
  }

  // ===== epilogue: write O interleaved-pair layout into o2 (for k4 staging) =====
  u16* dst = o2 + (size_t)b*33554432 + 16777216
                + (size_t)(c>>1)*524288 + (c&1);
  #pragma unroll
  for (int r=0;r<4;r++){
    float inv = 1.0f / l_run[r];
    int qq = q0 + wv*16 + l4*4 + r;
    #pragma unroll
    for (int n=0;n<32;n++){
      int w = n*16 + l15;
      dst[(size_t)qq*1024 + w*2] = f2bf(oacc[n][r]*inv);
    }
  }
}

// ---------------- K4: out conv + BN + residual (frozen) ----------
__global__ __launch_bounds__(512,2)
void k4_out(const u16* __restrict__ o2, const u16* __restrict__ wz,
            const float* __restrict__ dz, const float* __restrict__ f,
            float* __restrict__ out)
{
  int bid = blockIdx.x;
  int b = bid >> 9;
  int h = bid & 511;
  int tid = threadIdx.x, wv = tid>>6, lane = tid&63;
  int l15 = lane&15, l4 = lane>>4;

  __shared__ u16 Ost[32*1032];

  const u16* src0 = o2 + (size_t)b*33554432 + 16777216 + (size_t)h*1024;
  #pragma unroll
  for (int jj=0;jj<4;jj++){
    int row = jj*8 + wv;
    const u16* srow = src0 + (size_t)row*524288;
    #pragma unroll
    for (int hf=0;hf<2;hf++){
      gld16(srow + hf*512 + lane*8, &Ost[row*1032 + hf*512 + lane*8]);
    }
  }

  bf16x8 wa[4][2];
  #pragma unroll
  for (int m=0;m<4;m++)
    #pragma unroll
    for (int ks=0;ks<2;ks++){
      B8 t; t.q = *(const uint4*)(wz + 3*4096 + (m*16+l15)*64 + ks*32 + l4*8);
      wa[m][ks] = t.v;
    }
  f32x4 dvv[4];
  #pragma unroll
  for (int m=0;m<4;m++) dvv[m] = *(const f32x4*)(dz + 3*64 + m*16 + l4*4);

  asm volatile("s_waitcnt vmcnt(0)" ::: "memory");
  __syncthreads();

  f32x4 acc[4][4];
  #pragma unroll
  for (int m=0;m<4;m++)
    #pragma unroll
    for (int n=0;n<4;n++) acc[m][n] = (f32x4){0.f,0.f,0.f,0.f};

  const u16* obase = Ost + l4*4128 + wv*128 + l15*2;
  #pragma unroll
  for (int ks=0;ks<2;ks++){
    #pragma unroll
    for (int n=0;n<4;n++){
      B8 bb;
      #pragma unroll
      for (int jj=0;jj<4;jj++)
        bb.u[jj] = *(const u32*)(obase + ks*16512 + jj*1032 + n*32);
      #pragma unroll
      for (int m=0;m<4;m++)
        acc[m][n] = MFMA16(wa[m][ks], bb.v, acc[m][n]);
    }
  }
  #pragma unroll
  for (int m=0;m<4;m++)
    #pragma unroll
    for (int n=0;n<4;n++)
      #pragma unroll
      for (int r=0;r<4;r++){
        int o = m*16 + l4*4 + r;
        int w = wv*64 + n*16 + l15;
        size_t idx = ((size_t)(b*64+o)*512 + h)*512 + w;
        out[idx] = acc[m][n][r] + dvv[m][r] + f[idx];
      }
}

// ---------------- launch ----------------
extern "C" void kernel_launch(void* const* d_in, const int* in_sizes, int n_in,
                              void* d_out, int out_size, void* d_ws, size_t ws_size,
                              hipStream_t stream) {
  const float* feat = (const float*)d_in[0];
  char* ws = (char*)d_ws;
  u16*   wz   = (u16*)ws;
  float* dz   = (float*)(ws + 32768);
  u16* bufQ = (u16*)(ws + 65536);     // q
  u16* bufK = bufQ + 67108864ull;     // k
  u16* bufV = bufK + 67108864ull;     // vT hb-blocked [head][hb][w][8]
  u16* o2   = (u16*)d_out;            // O pair-layout scratch in d_out's per-b upper 32MB

  float extraK = 1.4426950408889634f / sqrtf(512.0f);  // fold 1/sqrt(W)*log2(e) into K
  k0_prep4<<<dim3(4), dim3(256), 0, stream>>>(
      (const float*)d_in[1],  (const float*)d_in[2],  (const float*)d_in[3],
      (const float*)d_in[4],  (const float*)d_in[5],  (const float*)d_in[6],
      (const float*)d_in[7],  (const float*)d_in[8],  (const float*)d_in[9],
      (const float*)d_in[10], (const float*)d_in[11], (const float*)d_in[12],
      (const float*)d_in[13], (const float*)d_in[14], (const float*)d_in[15],
      (const float*)d_in[16], (const float*)d_in[17], (const float*)d_in[18],
      (const float*)d_in[19], (const float*)d_in[20], (const float*)d_in[21],
      (const float*)d_in[22], (const float*)d_in[23], (const float*)d_in[24],
      extraK, wz, dz);
  k1_qkv   <<<dim3(1024), dim3(256), 0, stream>>>(feat, wz, dz, bufQ, bufK, bufV);
  k23_attn <<<dim3(1024), dim3(512), 0, stream>>>(bufQ, bufK, bufV, o2);
  k4_out   <<<dim3(2048), dim3(512), 0, stream>>>(o2, wz, dz, feat, (float*)d_out);
}

// Round 18
// 596.218 us; speedup vs baseline: 1.0910x; 1.0910x over previous
//
#include <hip/hip_runtime.h>
#include <math.h>

typedef unsigned short u16;
typedef unsigned int u32;
typedef unsigned long long u64;
typedef __attribute__((ext_vector_type(8))) short bf16x8;
typedef __attribute__((ext_vector_type(4))) float f32x4;

#define MFMA16(a,b,c) __builtin_amdgcn_mfma_f32_16x16x32_bf16(a,b,c,0,0,0)

typedef __attribute__((address_space(1))) const unsigned int as1_u32;
typedef __attribute__((address_space(3))) unsigned int as3_u32;
__device__ __forceinline__ void gld16(const u16* g, u16* l){
  __builtin_amdgcn_global_load_lds((as1_u32*)g, (as3_u32*)l, 16, 0, 0);
}

__device__ __forceinline__ u16 f2bf(float x){
  union { float f; u32 u; } v; v.f = x;
  u32 u = v.u;
  return (u16)((u + 0x7fffu + ((u>>16)&1u)) >> 16);
}

__device__ __forceinline__ void memfence(){ asm volatile("" ::: "memory"); }

union B8 { bf16x8 v; u32 u[4]; uint4 q; };

// ---------------- K0 (merged): fold BN into bf16 weights, all 4 sets ----------
__global__ void k0_prep4(
    const float* w0,const float* b0,const float* g0,const float* e0,const float* m0,const float* v0,
    const float* w1,const float* b1,const float* g1,const float* e1,const float* m1,const float* v1,
    const float* w2,const float* b2,const float* g2,const float* e2,const float* m2,const float* v2,
    const float* w3,const float* b3,const float* g3,const float* e3,const float* m3,const float* v3,
    float extraK, u16* wz, float* dz)
{
  int m = blockIdx.x;
  const float* W[4]={w0,w1,w2,w3}; const float* B[4]={b0,b1,b2,b3};
  const float* G[4]={g0,g1,g2,g3}; const float* E[4]={e0,e1,e2,e3};
  const float* M[4]={m0,m1,m2,m3}; const float* V[4]={v0,v1,v2,v3};
  const float* wm=W[m]; const float* bias=B[m]; const float* gamma=G[m];
  const float* beta=E[m]; const float* mean=M[m]; const float* var=V[m];
  float extra = (m==1) ? extraK : 1.0f;
  u16* wdst = wz + m*4096;
  float* ddst = dz + m*64;

  int t = threadIdx.x;
  if (t < 64){
    float a0 = gamma[t] * rsqrtf(var[t] + 1e-5f);
    ddst[t] = (beta[t] + (bias[t] - mean[t]) * a0) * extra;
  }
  for (int i = t; i < 4096; i += 256){
    int o = i >> 6;
    float a0 = gamma[o] * rsqrtf(var[o] + 1e-5f);
    wdst[i] = f2bf(wm[i] * a0 * extra);
  }
}

// ---------------- K1: QKV projection + BN; 16-h tiles, (256,3) ----------
__global__ __launch_bounds__(256,3)
void k1_qkv(const float* __restrict__ f, const u16* __restrict__ wz,
            const float* __restrict__ dz, u16* __restrict__ q,
            u16* __restrict__ kk_, u16* __restrict__ vt)
{
  int bid = blockIdx.x;
  int b  = bid >> 8;
  int ht = (bid >> 3) & 31;
  int wt = bid & 7;
  int tid = threadIdx.x;
  int wv = tid >> 6, lane = tid & 63;
  int l15 = lane & 15, l4 = lane >> 4;
  int h0 = ht * 16;
  int w0 = wt * 64 + wv * 16;

  bf16x8 wa[3][4][2];
  #pragma unroll
  for (int mt=0; mt<3; mt++)
    #pragma unroll
    for (int m=0;m<4;m++)
      #pragma unroll
      for (int ks=0;ks<2;ks++){
        B8 t; t.q = *(const uint4*)(wz + mt*4096 + (m*16+l15)*64 + ks*32 + l4*8);
        wa[mt][m][ks] = t.v;
      }
  f32x4 dv[3][4];
  #pragma unroll
  for (int mt=0;mt<3;mt++)
    #pragma unroll
    for (int m=0;m<4;m++)
      dv[mt][m] = *(const f32x4*)(dz + mt*64 + m*16 + l4*4);

  __shared__ u16 vstage[4][8704];
  u16* vs = vstage[wv];

  B8 bf[2];
  #pragma unroll
  for (int ks=0;ks<2;ks++)
    #pragma unroll
    for (int jj=0;jj<4;jj++){
      int c0 = ks*32 + l4*8 + jj*2;
      size_t i0 = ((size_t)(b*64 + c0)*512 + h0)*512 + w0 + l15;
      bf[ks].u[jj] = (u32)f2bf(f[i0]) | ((u32)f2bf(f[i0 + 262144]) << 16);
    }

  for (int hh=0; hh<16; hh++){
    int h = h0 + hh;
    B8 bfn[2];
    if (hh < 15){
      #pragma unroll
      for (int ks=0;ks<2;ks++)
        #pragma unroll
        for (int jj=0;jj<4;jj++){
          int c0 = ks*32 + l4*8 + jj*2;
          size_t i0 = ((size_t)(b*64 + c0)*512 + h + 1)*512 + w0 + l15;
          bfn[ks].u[jj] = (u32)f2bf(f[i0]) | ((u32)f2bf(f[i0 + 262144]) << 16);
        }
    }
    #pragma unroll
    for (int mt=0; mt<3; mt++){
      f32x4 acc[4];
      #pragma unroll
      for (int m=0;m<4;m++) acc[m] = (f32x4){0.f,0.f,0.f,0.f};
      #pragma unroll
      for (int m=0;m<4;m++)
        #pragma unroll
        for (int ks=0;ks<2;ks++)
          acc[m] = MFMA16(wa[mt][m][ks], bf[ks].v, acc[m]);
      #pragma unroll
      for (int m=0;m<4;m++)
        #pragma unroll
        for (int r=0;r<4;r++){
          float val = acc[m][r] + dv[mt][m][r];
          u16 bv = f2bf(val);
          int o = m*16 + l4*4 + r;
          if (mt==0)      q  [((size_t)(b*64+o)*512 + h)*512 + w0 + l15] = bv;
          else if (mt==1) kk_[((size_t)(b*64+o)*512 + h)*512 + w0 + l15] = bv;
          else            vs[o*136 + l15*8 + (hh&7)] = bv;
        }
    }
    bf[0] = bfn[0]; bf[1] = bfn[1];
    if ((hh&7)==7){
      __syncthreads();
      int hbg = (h - 7) >> 3;    // global 8-h block index
      #pragma unroll
      for (int rr=0; rr<16; rr++){
        int o = rr*4 + l4;
        uint4 d = *(const uint4*)(vs + o*136 + l15*8);
        *(uint4*)(vt + (size_t)(b*64+o)*262144 + (size_t)hbg*4096
                     + (size_t)(w0+l15)*8) = d;
      }
      __syncthreads();
    }
  }
}

// ---------------- K23 v11 (R13, frozen): flash attention, KB dbuf + VB single ----
__global__ __launch_bounds__(512,2)
void k23_attn(const u16* __restrict__ q, const u16* __restrict__ kten,
              const u16* __restrict__ vt, u16* __restrict__ o2)
{
  int phys = blockIdx.x;
  int x = phys & 7, j = phys >> 3;
  int qt = j & 3, hh = j >> 2;
  int head = x*32 + hh;
  int q0 = qt*128;
  int b = head >> 6, c = head & 63;

  int tid = threadIdx.x;
  int wv = tid >> 6, lane = tid & 63;
  int l15 = lane & 15, l4 = lane >> 4;

  const u16* qh = q    + (size_t)head*262144;
  const u16* kh = kten + (size_t)head*262144;
  const u16* vh = vt   + (size_t)head*262144;   // [hb(64)][w(512)][8h]

  __shared__ u16 KB[2][16640]; // [g 0..31][520] rows padded (1040B), double-buffered
  __shared__ u16 VB[16384];    // [w 0..511][4 granules]; slot cc holds hb (cc-(w>>1))&3
  __shared__ u16 Pt[5120];     // [q 0..127][40] wave-private rows

  auto stageK = [&](int jt, int buf){
    const u16* src = kh + (size_t)jt*16384;
    #pragma unroll
    for (int i=0;i<4;i++){
      int row = i*8 + wv;                       // wave-uniform per instruction
      gld16(src + (size_t)row*512 + lane*8, &KB[buf][row*520 + lane*8]);
    }
  };
  auto stageV = [&](int jt){
    const u16* src = vh + (size_t)jt*16384;     // 4 hb pages of 4096 elems
    #pragma unroll
    for (int i=0;i<4;i++){
      int slot = i*512 + tid;
      int w = slot >> 2, cc = slot & 3;
      int hbl = (cc - (w>>1)) & 3;              // hb page feeding this LDS slot
      gld16(src + hbl*4096 + w*8, &VB[slot*8]);
    }
  };

  // prologue: Q->regs first, then K0, V0, K1; wait all but K1
  uint4 qreg[16];
  {
    const u16* qrow = qh + (size_t)(q0 + wv*16 + l15)*512;
    #pragma unroll
    for (int ks=0;ks<16;ks++) qreg[ks] = *(const uint4*)(qrow + ks*32 + l4*8);
  }
  stageK(0, 0); stageV(0); stageK(1, 1);
  asm volatile("s_waitcnt vmcnt(4)" ::: "memory");
  __builtin_amdgcn_s_barrier(); memfence();

  f32x4 oacc[32];
  #pragma unroll
  for (int n=0;n<32;n++) oacc[n] = (f32x4){0.f,0.f,0.f,0.f};
  float m_run[4] = {-1e30f,-1e30f,-1e30f,-1e30f};
  float l_run[4] = {0.f,0.f,0.f,0.f};

  // per-lane LDS element bases; all loop offsets are compile-time immediates
  const int kbase = l15*520 + l4*8;                              // + n*8320 + ks*32
  const int vbase = l15*32  + (((l4 + (l15>>1)) & 3) << 3);      // + n*512
  const int pbase = (wv*16 + l15)*40;                            // + l4*8
  const int prow  = (wv*16 + l4*4)*40;                           // + r*40 + n*16 + l15

  for (int jt=0; jt<16; ++jt){
    int cur = jt & 1;
    const u16* Kc = &KB[cur][0];

    // ===== S phase: 32 MFMA on KB[cur] (K(jt) landed) =====
    f32x4 sA[2], sB[2];
    #pragma unroll
    for (int n=0;n<2;n++){ sA[n]=(f32x4){0,0,0,0}; sB[n]=(f32x4){0,0,0,0}; }
    __builtin_amdgcn_s_setprio(1);
    #pragma unroll
    for (int ks=0; ks<8; ++ks){
      B8 a; a.q = qreg[ks];
      #pragma unroll
      for (int n=0;n<2;n++){
        B8 bb; bb.q = *(const uint4*)(Kc + kbase + n*8320 + ks*32);
        sA[n] = MFMA16(a.v, bb.v, sA[n]);
      }
    }
    #pragma unroll
    for (int ks=8; ks<16; ++ks){
      B8 a; a.q = qreg[ks];
      #pragma unroll
      for (int n=0;n<2;n++){
        B8 bb; bb.q = *(const uint4*)(Kc + kbase + n*8320 + ks*32);
        sB[n] = MFMA16(a.v, bb.v, sB[n]);
      }
    }
    __builtin_amdgcn_s_setprio(0);
    f32x4 sacc0 = sA[0] + sB[0];
    f32x4 sacc1 = sA[1] + sB[1];

    // ===== wave-private online softmax (rows wv*16 + l4*4 + r), defer-max =====
    float pm[4], fc[4];
    bool need = false;
    #pragma unroll
    for (int r=0;r<4;r++){
      float p = fmaxf(sacc0[r], sacc1[r]);
      #pragma unroll
      for (int d=1; d<16; d<<=1) p = fmaxf(p, __shfl_xor(p, d, 64));
      pm[r] = p;
      need = need || (p > m_run[r] + 4.0f);
    }
    if (__any(need ? 1 : 0)){
      #pragma unroll
      for (int r=0;r<4;r++){
        float mn = fmaxf(m_run[r], pm[r]);
        fc[r] = exp2f(m_run[r] - mn);
        m_run[r] = mn;
      }
      #pragma unroll
      for (int n=0;n<32;n++)
        #pragma unroll
        for (int r=0;r<4;r++) oacc[n][r] *= fc[r];
    } else {
      fc[0]=fc[1]=fc[2]=fc[3]=1.0f;
    }
    #pragma unroll
    for (int r=0;r<4;r++){
      float e0 = exp2f(sacc0[r] - m_run[r]);
      float e1 = exp2f(sacc1[r] - m_run[r]);
      float s = e0 + e1;
      #pragma unroll
      for (int d=1; d<16; d<<=1) s += __shfl_xor(s, d, 64);
      l_run[r] = l_run[r]*fc[r] + s;
      Pt[prow + r*40 + l15]      = f2bf(e0);
      Pt[prow + r*40 + 16 + l15] = f2bf(e1);
    }

    // barrier 1: all waves done reading KB[cur] -> free for K(jt+2)
    asm volatile("s_waitcnt lgkmcnt(0)" ::: "memory");
    __builtin_amdgcn_s_barrier(); memfence();

    if (jt < 14) stageK(jt+2, cur);
    // in-order retirement: leaving only K(jt+2)'s 4 outstanding guarantees
    // V(jt) (prev iter) and K(jt+1) (two phases old) have landed.
    if (jt < 14)      { asm volatile("s_waitcnt vmcnt(4)" ::: "memory"); }
    else              { asm volatile("s_waitcnt vmcnt(0)" ::: "memory"); }
    __builtin_amdgcn_s_barrier(); memfence();   // barrier 2: everyone's V landed

    // ===== PV phase: O[own 16 q][512 w] += P(16x32) * V(32x512) =====
    B8 pa; pa.q = *(const uint4*)(Pt + pbase + l4*8);
    __builtin_amdgcn_s_setprio(1);
    #pragma unroll
    for (int n=0;n<32;n++){
      B8 bb; bb.q = *(const uint4*)(VB + vbase + n*512);
      oacc[n] = MFMA16(pa.v, bb.v, oacc[n]);
    }
    __builtin_amdgcn_s_setprio(0);

    if (jt < 15){
      // barrier 3: all waves done reading VB -> refill for V(jt+1)
      asm volatile("s_waitcnt lgkmcnt(0)" ::: "memory");
      __builtin_amdgcn_s_barrier(); memfence();
      stageV(jt+1);
      // no wait here: next iter's vmcnt(4) covers V(jt+1) before its PV.
    }
  }

  // ===== epilogue: write O interleaved-pair layout into o2 (for k4 staging) =====
  u16* dst = o2 + (size_t)b*33554432 + 16777216
                + (size_t)(c>>1)*524288 + (c&1);
  #pragma unroll
  for (int r=0;r<4;r++){
    float inv = 1.0f / l_run[r];
    int qq = q0 + wv*16 + l4*4 + r;
    #pragma unroll
    for (int n=0;n<32;n++){
      int w = n*16 + l15;
      dst[(size_t)qq*1024 + w*2] = f2bf(oacc[n][r]*inv);
    }
  }
}

// ---------------- K4: out conv + BN + residual (frozen) ----------
__global__ __launch_bounds__(512,2)
void k4_out(const u16* __restrict__ o2, const u16* __restrict__ wz,
            const float* __restrict__ dz, const float* __restrict__ f,
            float* __restrict__ out)
{
  int bid = blockIdx.x;
  int b = bid >> 9;
  int h = bid & 511;
  int tid = threadIdx.x, wv = tid>>6, lane = tid&63;
  int l15 = lane&15, l4 = lane>>4;

  __shared__ u16 Ost[32*1032];

  const u16* src0 = o2 + (size_t)b*33554432 + 16777216 + (size_t)h*1024;
  #pragma unroll
  for (int jj=0;jj<4;jj++){
    int row = jj*8 + wv;
    const u16* srow = src0 + (size_t)row*524288;
    #pragma unroll
    for (int hf=0;hf<2;hf++){
      gld16(srow + hf*512 + lane*8, &Ost[row*1032 + hf*512 + lane*8]);
    }
  }

  bf16x8 wa[4][2];
  #pragma unroll
  for (int m=0;m<4;m++)
    #pragma unroll
    for (int ks=0;ks<2;ks++){
      B8 t; t.q = *(const uint4*)(wz + 3*4096 + (m*16+l15)*64 + ks*32 + l4*8);
      wa[m][ks] = t.v;
    }
  f32x4 dvv[4];
  #pragma unroll
  for (int m=0;m<4;m++) dvv[m] = *(const f32x4*)(dz + 3*64 + m*16 + l4*4);

  asm volatile("s_waitcnt vmcnt(0)" ::: "memory");
  __syncthreads();

  f32x4 acc[4][4];
  #pragma unroll
  for (int m=0;m<4;m++)
    #pragma unroll
    for (int n=0;n<4;n++) acc[m][n] = (f32x4){0.f,0.f,0.f,0.f};

  const u16* obase = Ost + l4*4128 + wv*128 + l15*2;
  #pragma unroll
  for (int ks=0;ks<2;ks++){
    #pragma unroll
    for (int n=0;n<4;n++){
      B8 bb;
      #pragma unroll
      for (int jj=0;jj<4;jj++)
        bb.u[jj] = *(const u32*)(obase + ks*16512 + jj*1032 + n*32);
      #pragma unroll
      for (int m=0;m<4;m++)
        acc[m][n] = MFMA16(wa[m][ks], bb.v, acc[m][n]);
    }
  }
  #pragma unroll
  for (int m=0;m<4;m++)
    #pragma unroll
    for (int n=0;n<4;n++)
      #pragma unroll
      for (int r=0;r<4;r++){
        int o = m*16 + l4*4 + r;
        int w = wv*64 + n*16 + l15;
        size_t idx = ((size_t)(b*64+o)*512 + h)*512 + w;
        out[idx] = acc[m][n][r] + dvv[m][r] + f[idx];
      }
}

// ---------------- launch ----------------
extern "C" void kernel_launch(void* const* d_in, const int* in_sizes, int n_in,
                              void* d_out, int out_size, void* d_ws, size_t ws_size,
                              hipStream_t stream) {
  const float* feat = (const float*)d_in[0];
  char* ws = (char*)d_ws;
  u16*   wz   = (u16*)ws;
  float* dz   = (float*)(ws + 32768);
  u16* bufQ = (u16*)(ws + 65536);     // q
  u16* bufK = bufQ + 67108864ull;     // k
  u16* bufV = bufK + 67108864ull;     // vT hb-blocked [head][hb][w][8]
  u16* o2   = (u16*)d_out;            // O pair-layout scratch in d_out's per-b upper 32MB

  float extraK = 1.4426950408889634f / sqrtf(512.0f);  // fold 1/sqrt(W)*log2(e) into K
  k0_prep4<<<dim3(4), dim3(256), 0, stream>>>(
      (const float*)d_in[1],  (const float*)d_in[2],  (const float*)d_in[3],
      (const float*)d_in[4],  (const float*)d_in[5],  (const float*)d_in[6],
      (const float*)d_in[7],  (const float*)d_in[8],  (const float*)d_in[9],
      (const float*)d_in[10], (const float*)d_in[11], (const float*)d_in[12],
      (const float*)d_in[13], (const float*)d_in[14], (const float*)d_in[15],
      (const float*)d_in[16], (const float*)d_in[17], (const float*)d_in[18],
      (const float*)d_in[19], (const float*)d_in[20], (const float*)d_in[21],
      (const float*)d_in[22], (const float*)d_in[23], (const float*)d_in[24],
      extraK, wz, dz);
  k1_qkv   <<<dim3(1024), dim3(256), 0, stream>>>(feat, wz, dz, bufQ, bufK, bufV);
  k23_attn <<<dim3(1024), dim3(512), 0, stream>>>(bufQ, bufK, bufV, o2);
  k4_out   <<<dim3(2048), dim3(512), 0, stream>>>(o2, wz, dz, feat, (float*)d_out);
}